// Round 2
// baseline (815.322 us; speedup 1.0000x reference)
//
#include <hip/hip_runtime.h>

// Problem constants (fixed by setup_inputs): b=16, s=4096, h=16, p=64, n=64
constexpr int S  = 4096;
constexpr int H  = 16;
constexpr int P  = 64;
constexpr int NN = 64;
constexpr int PAIRS = 256;          // b*h
constexpr int KSPLIT = 8;           // K-dim split across blocks
constexpr int TT = 16;              // t-rows staged per LDS tile
constexpr int LDP = 72;             // padded LDS row stride (floats) - spreads staging writes over banks
constexpr float WMIN = 1e-12f;      // dropped terms sum to < ~3e-11 abs error

// Kernel 1: per (b,h) pair, w[t] = exp(sum of A over positions t+1 .. s-1),
// plus the first index where w >= WMIN (w is monotone nondecreasing: A <= 0).
__global__ __launch_bounds__(256) void scan_w(const float* __restrict__ A,
                                              float* __restrict__ w,
                                              int* __restrict__ cut) {
    const int pair = blockIdx.x;          // 0..255
    const int b = pair >> 4, h = pair & 15;
    const float* Ab = A + (size_t)b * S * H + h;   // element t at Ab[t*H]
    const int j = threadIdx.x;            // 0..255, owns t in [j*16, j*16+16)

    float a[16];
    float lsum = 0.f;
#pragma unroll
    for (int i = 0; i < 16; ++i) {
        a[i] = Ab[(size_t)(j * 16 + i) * H];
        lsum += a[i];
    }

    __shared__ float sd[256];
    __shared__ int   ci[256];
    sd[j] = lsum;
    __syncthreads();
    float incl = lsum;
    for (int off = 1; off < 256; off <<= 1) {
        float add = (j >= off) ? sd[j - off] : 0.f;
        __syncthreads();
        incl += add;
        sd[j] = incl;
        __syncthreads();
    }
    const float total = sd[255];
    float run = incl - lsum;  // exclusive prefix at this thread's first element

    float* wrow = w + (size_t)pair * S + j * 16;
    int firstIdx = S;
#pragma unroll
    for (int i = 0; i < 16; ++i) {
        run += a[i];
        const float wv = expf(total - run);  // underflows to 0 for early t: fine
        wrow[i] = wv;
        if (wv >= WMIN && firstIdx == S) firstIdx = j * 16 + i;  // monotone: first hit
    }

    ci[j] = firstIdx;
    __syncthreads();
    for (int off = 128; off > 0; off >>= 1) {
        if (j < off) ci[j] = min(ci[j], ci[j + off]);
        __syncthreads();
    }
    if (j == 0) cut[pair] = ci[0];
}

// Kernel 2: out[pair][p][n] += sum_{t >= c0} w[t] * X[t][p] * B[t][n]
// 128 threads = 2 waves; each wave computes the full 64x64 with 8x8/thread
// over its own 8 rows of the 16-row tile; partials merged via LDS.
__global__ __launch_bounds__(128, 4) void mainK(const float* __restrict__ X,
                                                const float* __restrict__ Bm,
                                                const float* __restrict__ w,
                                                const int* __restrict__ cut,
                                                float* __restrict__ out) {
    const int pair = blockIdx.x;   // 0..255
    const int ks   = blockIdx.y;   // 0..KSPLIT-1
    const int b = pair >> 4, h = pair & 15;
    const int tid  = threadIdx.x;
    const int wave = tid >> 6;
    const int lane = tid & 63;

    const float* wrow = w + (size_t)pair * S;

    // cutoff from scan_w: align down to tile granularity (extra rows have w~0)
    const int c0 = min(S - TT, cut[pair] & ~(TT - 1));

    // balanced K partition of [c0, S) across the KSPLIT blocks
    const int nTiles = (S - c0) >> 4;
    const int tpb = (nTiles + KSPLIT - 1) / KSPLIT;
    const int i0 = ks * tpb;
    const int i1 = min(nTiles, i0 + tpb);
    if (i0 >= i1) return;   // uniform per block

    const float* Xp = X  + (size_t)b * S * H * P  + (size_t)h * P;   // + t*(H*P) + p
    const float* Bp = Bm + (size_t)b * S * H * NN + (size_t)h * NN;  // + t*(H*NN) + n

    __shared__ float smem[2 * TT * LDP];   // Xs | Bs ; reused as reduce buffer
    float* Xs = smem;                      // Xs[r][c] = smem[r*LDP + c], pre-scaled by w
    float* Bs = smem + TT * LDP;

    // staging map: thread stages 8 floats of X and 8 of B in row sr
    const int sr = tid >> 3;          // 0..15
    const int c8 = (tid & 7) * 8;     // 0,8,..,56

    // output map: 8x8 per thread; 8 lanes share tp (X broadcast), 8 share tn
    const int tp = (lane >> 3) * 8;
    const int tn = (lane & 7) * 8;
    const int r0 = wave * 8;          // this wave's row window in the tile

    float acc[64];
#pragma unroll
    for (int k = 0; k < 64; ++k) acc[k] = 0.f;

    // software pipeline: prefetch tile i+1 into registers during tile i compute
    int t = c0 + i0 * TT + sr;
    float  wv  = wrow[t];
    float4 xa0 = *(const float4*)(Xp + (size_t)t * (H * P)  + c8);
    float4 xa1 = *(const float4*)(Xp + (size_t)t * (H * P)  + c8 + 4);
    float4 ba0 = *(const float4*)(Bp + (size_t)t * (H * NN) + c8);
    float4 ba1 = *(const float4*)(Bp + (size_t)t * (H * NN) + c8 + 4);

    for (int i = i0; i < i1; ++i) {
        __syncthreads();  // previous tile's compute done before overwrite
        *(float4*)(&Xs[sr * LDP + c8])     = make_float4(xa0.x * wv, xa0.y * wv, xa0.z * wv, xa0.w * wv);
        *(float4*)(&Xs[sr * LDP + c8 + 4]) = make_float4(xa1.x * wv, xa1.y * wv, xa1.z * wv, xa1.w * wv);
        *(float4*)(&Bs[sr * LDP + c8])     = ba0;
        *(float4*)(&Bs[sr * LDP + c8 + 4]) = ba1;
        __syncthreads();

        if (i + 1 < i1) {   // uniform branch: prefetch next tile
            t = c0 + (i + 1) * TT + sr;
            wv  = wrow[t];
            xa0 = *(const float4*)(Xp + (size_t)t * (H * P)  + c8);
            xa1 = *(const float4*)(Xp + (size_t)t * (H * P)  + c8 + 4);
            ba0 = *(const float4*)(Bp + (size_t)t * (H * NN) + c8);
            ba1 = *(const float4*)(Bp + (size_t)t * (H * NN) + c8 + 4);
        }

#pragma unroll
        for (int r8 = 0; r8 < 8; ++r8) {
            const int r = r0 + r8;
            const float4 x0 = *(const float4*)(&Xs[r * LDP + tp]);
            const float4 x1 = *(const float4*)(&Xs[r * LDP + tp + 4]);
            const float4 b0 = *(const float4*)(&Bs[r * LDP + tn]);
            const float4 b1 = *(const float4*)(&Bs[r * LDP + tn + 4]);
            const float xa[8] = {x0.x, x0.y, x0.z, x0.w, x1.x, x1.y, x1.z, x1.w};
            const float ba[8] = {b0.x, b0.y, b0.z, b0.w, b1.x, b1.y, b1.z, b1.w};
#pragma unroll
            for (int ii = 0; ii < 8; ++ii)
#pragma unroll
                for (int jj = 0; jj < 8; ++jj)
                    acc[ii * 8 + jj] = fmaf(xa[ii], ba[jj], acc[ii * 8 + jj]);
        }
    }

    // merge wave1's partial into wave0 via LDS, two 8KB chunks (stride-1: conflict-free)
#pragma unroll
    for (int c = 0; c < 2; ++c) {
        __syncthreads();
        if (wave == 1) {
#pragma unroll
            for (int k = 0; k < 32; ++k) smem[k * 64 + lane] = acc[c * 32 + k];
        }
        __syncthreads();
        if (wave == 0) {
#pragma unroll
            for (int k = 0; k < 32; ++k) acc[c * 32 + k] += smem[k * 64 + lane];
        }
    }

    if (wave == 0) {
        float* op = out + (size_t)pair * (P * NN);
#pragma unroll
        for (int k = 0; k < 64; ++k)
            atomicAdd(&op[(size_t)(tp + (k >> 3)) * NN + tn + (k & 7)], acc[k]);
    }
}

extern "C" void kernel_launch(void* const* d_in, const int* in_sizes, int n_in,
                              void* d_out, int out_size, void* d_ws, size_t ws_size,
                              hipStream_t stream) {
    const float* X = (const float*)d_in[0];
    const float* A = (const float*)d_in[1];
    const float* B = (const float*)d_in[2];
    // d_in[3] = C is computed-then-discarded by the reference: never read.
    float* out = (float*)d_out;
    float* w   = (float*)d_ws;                          // PAIRS*S floats = 4 MiB
    int*   cut = (int*)((char*)d_ws + (size_t)PAIRS * S * sizeof(float));  // +1 KiB

    hipMemsetAsync(d_out, 0, (size_t)out_size * sizeof(float), stream);
    scan_w<<<PAIRS, 256, 0, stream>>>(A, w, cut);
    mainK<<<dim3(PAIRS, KSPLIT), 128, 0, stream>>>(X, B, w, cut, out);
}

// Round 3
// 715.984 us; speedup vs baseline: 1.1387x; 1.1387x over previous
//
#include <hip/hip_runtime.h>

// Problem constants (fixed by setup_inputs): b=16, s=4096, h=16, p=64, n=64
constexpr int S  = 4096;
constexpr int H  = 16;
constexpr int P  = 64;
constexpr int NN = 64;
constexpr int PAIRS = 256;          // b*h
constexpr int KSPLIT = 8;           // K-dim split across blocks
constexpr int TT = 16;              // t-rows staged per LDS tile
constexpr int LDP = 72;             // padded LDS row stride (floats)
constexpr float WMIN = 1e-12f;      // dropped terms sum to < ~3e-11 abs error

// Kernel 1: per (b,h) pair, w[t] = exp(sum of A over positions t+1 .. s-1),
// plus the first index where w >= WMIN (w is monotone nondecreasing: A <= 0).
__global__ __launch_bounds__(256) void scan_w(const float* __restrict__ A,
                                              float* __restrict__ w,
                                              int* __restrict__ cut) {
    const int pair = blockIdx.x;          // 0..255
    const int b = pair >> 4, h = pair & 15;
    const float* Ab = A + (size_t)b * S * H + h;   // element t at Ab[t*H]
    const int j = threadIdx.x;            // 0..255, owns t in [j*16, j*16+16)

    float a[16];
    float lsum = 0.f;
#pragma unroll
    for (int i = 0; i < 16; ++i) {
        a[i] = Ab[(size_t)(j * 16 + i) * H];
        lsum += a[i];
    }

    __shared__ float sd[256];
    __shared__ int   ci[256];
    sd[j] = lsum;
    __syncthreads();
    float incl = lsum;
    for (int off = 1; off < 256; off <<= 1) {
        float add = (j >= off) ? sd[j - off] : 0.f;
        __syncthreads();
        incl += add;
        sd[j] = incl;
        __syncthreads();
    }
    const float total = sd[255];
    float run = incl - lsum;  // exclusive prefix at this thread's first element

    float* wrow = w + (size_t)pair * S + j * 16;
    int firstIdx = S;
#pragma unroll
    for (int i = 0; i < 16; ++i) {
        run += a[i];
        const float wv = expf(total - run);  // underflows to 0 for early t: fine
        wrow[i] = wv;
        if (wv >= WMIN && firstIdx == S) firstIdx = j * 16 + i;  // monotone: first hit
    }

    ci[j] = firstIdx;
    __syncthreads();
    for (int off = 128; off > 0; off >>= 1) {
        if (j < off) ci[j] = min(ci[j], ci[j + off]);
        __syncthreads();
    }
    if (j == 0) cut[pair] = ci[0];
}

// Kernel 2: out[pair][p][n] += sum_{t >= c0} w[t] * X[t][p] * B[t][n]
// 128 threads = 2 waves; each wave computes the full 64x64 with 8x8/thread
// over its own 8 rows of the 16-row tile; partials merged via LDS.
// launch_bounds(128, 2): 256-VGPR budget. (128,4) capped at 128 and SPILLED
// the 64-float accumulator to scratch -> 599 MB/dispatch of spill writes (R2).
__global__ __launch_bounds__(128, 2) void mainK(const float* __restrict__ X,
                                                const float* __restrict__ Bm,
                                                const float* __restrict__ w,
                                                const int* __restrict__ cut,
                                                float* __restrict__ out) {
    const int pair = blockIdx.x;   // 0..255
    const int ks   = blockIdx.y;   // 0..KSPLIT-1
    const int b = pair >> 4, h = pair & 15;
    const int tid  = threadIdx.x;
    const int wave = tid >> 6;
    const int lane = tid & 63;

    const float* wrow = w + (size_t)pair * S;

    // cutoff from scan_w: align down to tile granularity (extra rows have w~0)
    const int c0 = min(S - TT, cut[pair] & ~(TT - 1));

    // balanced K partition of [c0, S) across the KSPLIT blocks
    const int nTiles = (S - c0) >> 4;
    const int tpb = (nTiles + KSPLIT - 1) / KSPLIT;
    const int i0 = ks * tpb;
    const int i1 = min(nTiles, i0 + tpb);
    if (i0 >= i1) return;   // uniform per block

    const float* Xp = X  + (size_t)b * S * H * P  + (size_t)h * P;   // + t*(H*P) + p
    const float* Bp = Bm + (size_t)b * S * H * NN + (size_t)h * NN;  // + t*(H*NN) + n

    __shared__ float smem[2 * TT * LDP];   // Xs | Bs ; reused as reduce buffer
    float* Xs = smem;                      // Xs[r][c] = smem[r*LDP + c], pre-scaled by w
    float* Bs = smem + TT * LDP;

    // staging map: thread stages 8 floats of X and 8 of B in row sr
    const int sr = tid >> 3;          // 0..15
    const int c8 = (tid & 7) * 8;     // 0,8,..,56

    // output map: 8x8 per thread; 8 lanes share tp (X broadcast), 8 share tn
    const int tp = (lane >> 3) * 8;
    const int tn = (lane & 7) * 8;
    const int r0 = wave * 8;          // this wave's row window in the tile

    float acc[64];
#pragma unroll
    for (int k = 0; k < 64; ++k) acc[k] = 0.f;

    // software pipeline: prefetch tile i+1 into registers during tile i compute
    int t = c0 + i0 * TT + sr;
    float  wv  = wrow[t];
    float4 xa0 = *(const float4*)(Xp + (size_t)t * (H * P)  + c8);
    float4 xa1 = *(const float4*)(Xp + (size_t)t * (H * P)  + c8 + 4);
    float4 ba0 = *(const float4*)(Bp + (size_t)t * (H * NN) + c8);
    float4 ba1 = *(const float4*)(Bp + (size_t)t * (H * NN) + c8 + 4);

    for (int i = i0; i < i1; ++i) {
        __syncthreads();  // previous tile's compute done before overwrite
        *(float4*)(&Xs[sr * LDP + c8])     = make_float4(xa0.x * wv, xa0.y * wv, xa0.z * wv, xa0.w * wv);
        *(float4*)(&Xs[sr * LDP + c8 + 4]) = make_float4(xa1.x * wv, xa1.y * wv, xa1.z * wv, xa1.w * wv);
        *(float4*)(&Bs[sr * LDP + c8])     = ba0;
        *(float4*)(&Bs[sr * LDP + c8 + 4]) = ba1;
        __syncthreads();

        if (i + 1 < i1) {   // uniform branch: prefetch next tile
            t = c0 + (i + 1) * TT + sr;
            wv  = wrow[t];
            xa0 = *(const float4*)(Xp + (size_t)t * (H * P)  + c8);
            xa1 = *(const float4*)(Xp + (size_t)t * (H * P)  + c8 + 4);
            ba0 = *(const float4*)(Bp + (size_t)t * (H * NN) + c8);
            ba1 = *(const float4*)(Bp + (size_t)t * (H * NN) + c8 + 4);
        }

#pragma unroll
        for (int r8 = 0; r8 < 8; ++r8) {
            const int r = r0 + r8;
            const float4 x0 = *(const float4*)(&Xs[r * LDP + tp]);
            const float4 x1 = *(const float4*)(&Xs[r * LDP + tp + 4]);
            const float4 b0 = *(const float4*)(&Bs[r * LDP + tn]);
            const float4 b1 = *(const float4*)(&Bs[r * LDP + tn + 4]);
            const float xa[8] = {x0.x, x0.y, x0.z, x0.w, x1.x, x1.y, x1.z, x1.w};
            const float ba[8] = {b0.x, b0.y, b0.z, b0.w, b1.x, b1.y, b1.z, b1.w};
#pragma unroll
            for (int ii = 0; ii < 8; ++ii)
#pragma unroll
                for (int jj = 0; jj < 8; ++jj)
                    acc[ii * 8 + jj] = fmaf(xa[ii], ba[jj], acc[ii * 8 + jj]);
        }
    }

    // merge wave1's partial into wave0 via LDS, two chunks (stride-1: conflict-free)
#pragma unroll
    for (int c = 0; c < 2; ++c) {
        __syncthreads();
        if (wave == 1) {
#pragma unroll
            for (int k = 0; k < 32; ++k) smem[k * 64 + lane] = acc[c * 32 + k];
        }
        __syncthreads();
        if (wave == 0) {
#pragma unroll
            for (int k = 0; k < 32; ++k) acc[c * 32 + k] += smem[k * 64 + lane];
        }
    }

    if (wave == 0) {
        float* op = out + (size_t)pair * (P * NN);
#pragma unroll
        for (int k = 0; k < 64; ++k)
            atomicAdd(&op[(size_t)(tp + (k >> 3)) * NN + tn + (k & 7)], acc[k]);
    }
}

extern "C" void kernel_launch(void* const* d_in, const int* in_sizes, int n_in,
                              void* d_out, int out_size, void* d_ws, size_t ws_size,
                              hipStream_t stream) {
    const float* X = (const float*)d_in[0];
    const float* A = (const float*)d_in[1];
    const float* B = (const float*)d_in[2];
    // d_in[3] = C is computed-then-discarded by the reference: never read.
    float* out = (float*)d_out;
    float* w   = (float*)d_ws;                          // PAIRS*S floats = 4 MiB
    int*   cut = (int*)((char*)d_ws + (size_t)PAIRS * S * sizeof(float));  // +1 KiB

    hipMemsetAsync(d_out, 0, (size_t)out_size * sizeof(float), stream);
    scan_w<<<PAIRS, 256, 0, stream>>>(A, w, cut);
    mainK<<<dim3(PAIRS, KSPLIT), 128, 0, stream>>>(X, B, w, cut, out);
}